// Round 10
// baseline (726.750 us; speedup 1.0000x reference)
//
#include <hip/hip_runtime.h>
#include <hip/hip_bf16.h>
#include <cstdint>
#include <cstddef>

#define N_NODES 20000
#define N_EDGES 640000
#define HID     128
#define OUT_DIM 64
#define NSTEPS  16
#define HSTEP   0.1f
#define H2      0.01f          // HSTEP^2 (leapfrog coefficient)
#define NBLK    625            // N_NODES / 32

typedef unsigned short u16;
typedef __attribute__((ext_vector_type(8))) short short8;   // 8 bf16 (4 VGPRs)
typedef __attribute__((ext_vector_type(4))) float f32x4;    // MFMA C/D

__device__ __forceinline__ float bf2f(u16 u) {
    union { unsigned int i; float f; } v; v.i = ((unsigned int)u) << 16; return v.f;
}
__device__ __forceinline__ u16 f2bf(float f) {
    union { float f; unsigned int i; } v; v.f = f;
    unsigned int x = v.i;
    unsigned int r = x + 0x7FFFu + ((x >> 16) & 1u);   // round-to-nearest-even
    return (u16)(r >> 16);
}

__device__ __forceinline__ float sigm(float x) { return 1.f / (1.f + __expf(-x)); }
__device__ __forceinline__ float tanh_fast(float x) {
    float e2 = __expf(-2.f * fabsf(x));
    float t = (1.f - e2) / (1.f + e2);
    return copysignf(t, x);
}

// fast variants (raw v_rcp_f32, rel err ~1e-6 — far below bf16 noise)
__device__ __forceinline__ float rcp_f(float x) { return __builtin_amdgcn_rcpf(x); }
__device__ __forceinline__ float sigm_f(float x) {
    return rcp_f(1.f + __expf(-x));
}
__device__ __forceinline__ float tanh_f(float x) {
    float e2 = __expf(-2.f * fabsf(x));
    float t = (1.f - e2) * rcp_f(1.f + e2);
    return copysignf(t, x);
}

// ---------------------------------------------------------------------------
// Storage-dtype detection. flag=1 -> tensors stored as f32; flag=0 -> bf16.
// ---------------------------------------------------------------------------
__global__ void detect_kernel(const u16* __restrict__ xraw, int* __restrict__ flag) {
    __shared__ int cnt;
    if (threadIdx.x == 0) cnt = 0;
    __syncthreads();
    int c = 0;
    for (int i = threadIdx.x; i < 4096; i += 256) {
        int e = (xraw[i] >> 7) & 0xFF;
        if (e >= 0x90) c++;
    }
    atomicAdd(&cnt, c);
    __syncthreads();
    if (threadIdx.x == 0) *flag = (cnt > 100) ? 1 : 0;
}

// ---------------------------------------------------------------------------
// Packed conversion of the 15 weight/bias tensors into contiguous f32 ws.
// ---------------------------------------------------------------------------
#define N_CVT 15
struct CvtArgs { const void* s[N_CVT]; };
__constant__ const int cvt_off[N_CVT + 1] = {
    0, 16384, 16512, 32896, 33024, 98560, 164096, 164608, 165120,
    230656, 231168, 231680, 264448, 264576, 272768, 272832 };

__global__ void convert_kernel(CvtArgs a, float* __restrict__ dst,
                               const int* __restrict__ flag) {
    int i = blockIdx.x * blockDim.x + threadIdx.x;
    if (i >= 272832) return;
    int seg = 0;
    #pragma unroll
    for (int s = 1; s < N_CVT; ++s) if (i >= cvt_off[s]) seg = s;
    int j = i - cvt_off[seg];
    float v = (*flag) ? ((const float*)a.s[seg])[j]
                      : bf2f(((const u16*)a.s[seg])[j]);
    dst[i] = v;
}

// ---------------------------------------------------------------------------
// Build bf16 weights in MFMA B-fragment-swizzled order.
// elem (nt, ck, lane, j) = W[nt*16 + (lane&15)][ck*32 + (lane>>4)*8 + j]
// flat o = ((nt*NCK + ck)*64 + lane)*8 + j.
// ---------------------------------------------------------------------------
__global__ void build_wswz_kernel(const float* __restrict__ wsf,
                                  u16* __restrict__ WswzF, u16* __restrict__ WswzB,
                                  u16* __restrict__ WswzH, u16* __restrict__ WswzO,
                                  u16* __restrict__ WswzE1, u16* __restrict__ WswzE2) {
    int o = blockIdx.x * blockDim.x + threadIdx.x;
    if (o < 131072) {   // forward [Wihf|Whhf], NCK=8
        int j = o & 7, l = (o >> 3) & 63, rest = o >> 9;
        int ck = rest & 7, nt = rest >> 3;
        int n = nt * 16 + (l & 15);
        int k = ck * 32 + (l >> 4) * 8 + j;
        const float* Wihf = wsf + 33024;
        const float* Whhf = wsf + 98560;
        float v = (k < 128) ? Wihf[n * 128 + k] : Whhf[n * 128 + (k - 128)];
        WswzF[o] = f2bf(v);
    }
    if (o < 65536) {    // backward Wihb, NCK=4
        int j = o & 7, l = (o >> 3) & 63, rest = o >> 9;
        int ck = rest & 3, nt = rest >> 2;
        int n = nt * 16 + (l & 15);
        int k = ck * 32 + (l >> 4) * 8 + j;
        const float* Wihb = wsf + 165120;
        WswzB[o] = f2bf(Wihb[n * 128 + k]);
    }
    if (o < 32768) {    // fc1 Wf1 [128][256], NCK=8
        int j = o & 7, l = (o >> 3) & 63, rest = o >> 9;
        int ck = rest & 7, nt = rest >> 3;
        int n = nt * 16 + (l & 15);
        int k = ck * 32 + (l >> 4) * 8 + j;
        const float* Wf1 = wsf + 231680;
        WswzH[o] = f2bf(Wf1[n * 256 + k]);
    }
    if (o < 8192) {     // fc2 Wf2 [64][128], NCK=4
        int j = o & 7, l = (o >> 3) & 63, rest = o >> 9;
        int ck = rest & 3, nt = rest >> 2;
        int n = nt * 16 + (l & 15);
        int k = ck * 32 + (l >> 4) * 8 + j;
        const float* Wf2 = wsf + 264576;
        WswzO[o] = f2bf(Wf2[n * 128 + k]);
    }
    if (o < 16384) {    // enc1 Wenc1 [128][128], NCK=4, and enc2 Wenc2
        int j = o & 7, l = (o >> 3) & 63, rest = o >> 9;
        int ck = rest & 3, nt = rest >> 2;
        int n = nt * 16 + (l & 15);
        int k = ck * 32 + (l >> 4) * 8 + j;
        const float* We1 = wsf + 0;
        const float* We2 = wsf + 16512;
        WswzE1[o] = f2bf(We1[n * 128 + k]);
        WswzE2[o] = f2bf(We2[n * 128 + k]);
    }
}

// ---------------------------------------------------------------------------
// CSR build: degree count -> exclusive scan -> bucket fill
// ---------------------------------------------------------------------------
__global__ void count_kernel(const int* __restrict__ ei, int* __restrict__ deg) {
    int e = blockIdx.x * blockDim.x + threadIdx.x;
    if (e < N_EDGES) atomicAdd(&deg[ei[N_EDGES + e]], 1);
}

__global__ __launch_bounds__(1024) void scan_kernel(const int* __restrict__ deg,
                                                    int* __restrict__ rowptr,
                                                    float* __restrict__ degf) {
    __shared__ int sd[1024];
    const int t = threadIdx.x;
    const int CH = (N_NODES + 1023) / 1024;   // 20
    int base = t * CH;
    int s = 0;
    for (int i = 0; i < CH; ++i) {
        int idx = base + i;
        if (idx < N_NODES) s += deg[idx];
    }
    sd[t] = s;
    __syncthreads();
    for (int off = 1; off < 1024; off <<= 1) {
        int v = (t >= off) ? sd[t - off] : 0;
        __syncthreads();
        sd[t] += v;
        __syncthreads();
    }
    int run = (t == 0) ? 0 : sd[t - 1];
    for (int i = 0; i < CH; ++i) {
        int idx = base + i;
        if (idx < N_NODES) {
            rowptr[idx] = run;
            degf[idx] = (float)deg[idx];
            run += deg[idx];
        }
    }
    if (t == 1023) rowptr[N_NODES] = sd[1023];
}

__global__ void fill_kernel(const int* __restrict__ ei, const int* __restrict__ rowptr,
                            int* __restrict__ fill, int* __restrict__ csr) {
    int e = blockIdx.x * blockDim.x + threadIdx.x;
    if (e < N_EDGES) {
        int d = ei[N_EDGES + e];
        int p = atomicAdd(&fill[d], 1);
        csr[rowptr[d] + p] = ei[e];
    }
}

// ---------------------------------------------------------------------------
// Fused encoder (one dispatch): enc1 -> H1 (LDS bf16) -> enc2 -> Xa + Xsnap0.
// ---------------------------------------------------------------------------
__global__ __launch_bounds__(512) void encoder_kernel(
    const void* __restrict__ xv,
    const u16* __restrict__ WswzE1, const u16* __restrict__ WswzE2,
    const float* __restrict__ benc1, const float* __restrict__ benc2,
    float* __restrict__ Xa, u16* __restrict__ Xsnap0, const int* __restrict__ flag)
{
    __shared__ __align__(16) u16 H1[32][136];
    const int w = threadIdx.x >> 6;
    const int l = threadIdx.x & 63;
    const int l15 = l & 15, quad = l >> 4;
    const int m0 = blockIdx.x * 32;
    const int kof = quad * 8;
    const int j = w * 16 + l15;
    const bool xf32 = (*flag != 0);

    f32x4 acc[2] = {};
    #pragma unroll
    for (int ck = 0; ck < 4; ++ck) {
        const int kc = ck * 32;
        short8 a0, a1;
        if (xf32) {
            const float* r0 = (const float*)xv + (size_t)(m0 + l15) * HID + kc + kof;
            const float* r1 = (const float*)xv + (size_t)(m0 + 16 + l15) * HID + kc + kof;
            union { u16 u[8]; short8 v; } t0, t1;
            #pragma unroll
            for (int e = 0; e < 8; ++e) { t0.u[e] = f2bf(r0[e]); t1.u[e] = f2bf(r1[e]); }
            a0 = t0.v; a1 = t1.v;
        } else {
            a0 = *(const short8*)((const u16*)xv + (size_t)(m0 + l15) * HID + kc + kof);
            a1 = *(const short8*)((const u16*)xv + (size_t)(m0 + 16 + l15) * HID + kc + kof);
        }
        short8 b = *(const short8*)(WswzE1 + (((size_t)(w * 4 + ck)) << 9) + (l << 3));
        acc[0] = __builtin_amdgcn_mfma_f32_16x16x32_bf16(a0, b, acc[0], 0, 0, 0);
        acc[1] = __builtin_amdgcn_mfma_f32_16x16x32_bf16(a1, b, acc[1], 0, 0, 0);
    }
    {
        const float bj = benc1[j];
        #pragma unroll
        for (int mt = 0; mt < 2; ++mt)
            #pragma unroll
            for (int i = 0; i < 4; ++i)
                H1[mt * 16 + quad * 4 + i][j] = f2bf(fmaxf(acc[mt][i] + bj, 0.f));
    }
    __syncthreads();

    f32x4 acc2[2] = {};
    #pragma unroll
    for (int ck = 0; ck < 4; ++ck) {
        const int kc = ck * 32;
        short8 a0 = *(const short8*)(&H1[l15][kc + kof]);
        short8 a1 = *(const short8*)(&H1[16 + l15][kc + kof]);
        short8 b = *(const short8*)(WswzE2 + (((size_t)(w * 4 + ck)) << 9) + (l << 3));
        acc2[0] = __builtin_amdgcn_mfma_f32_16x16x32_bf16(a0, b, acc2[0], 0, 0, 0);
        acc2[1] = __builtin_amdgcn_mfma_f32_16x16x32_bf16(a1, b, acc2[1], 0, 0, 0);
    }
    {
        const float bj = benc2[j];
        #pragma unroll
        for (int mt = 0; mt < 2; ++mt)
            #pragma unroll
            for (int i = 0; i < 4; ++i) {
                int m = m0 + mt * 16 + quad * 4 + i;
                float o = acc2[mt][i] + bj;
                Xa[(size_t)m * HID + j] = o;
                Xsnap0[(size_t)m * HID + j] = f2bf(o);
            }
    }
}

// ---------------------------------------------------------------------------
// Wave step — LEAPFROG. Round-4 body + 32-edge deep chunk (8 gathers in
// flight; code correctness-proven in round 6's fused kernel). Standalone the
// VGPR cost (~76) only drops occupancy 8->6-7 waves/SIMD, while doubling
// memory-level parallelism on the latency-bound gather.
// ---------------------------------------------------------------------------
template<bool FIRST>
__global__ __launch_bounds__(256) void wave_kernel(
    const float* __restrict__ Xcur, float* __restrict__ Xdst,
    const u16* __restrict__ XbfP, u16* __restrict__ XbfN,
    const float* __restrict__ degf,
    const int* __restrict__ rowptr, const int* __restrict__ csr)
{
    const int node = blockIdx.x * 4 + (threadIdx.x >> 6);
    const int lane = threadIdx.x & 63;
    const int q = lane >> 4;             // edge quarter 0..3
    const int fl = (lane & 15) * 8;      // 8 features per lane

    const int beg = rowptr[node], end = rowptr[node + 1];
    float s0[8] = {}, s1[8] = {}, s2[8] = {}, s3[8] = {};

    int i = beg;
    for (; i + 32 <= end; i += 32) {     // 8 gathers in flight
        int v0 = csr[i + 0 + q];
        int v1 = csr[i + 4 + q];
        int v2 = csr[i + 8 + q];
        int v3 = csr[i + 12 + q];
        int v4 = csr[i + 16 + q];
        int v5 = csr[i + 20 + q];
        int v6 = csr[i + 24 + q];
        int v7 = csr[i + 28 + q];
        short8 g0 = *(const short8*)(XbfP + (size_t)v0 * HID + fl);
        short8 g1 = *(const short8*)(XbfP + (size_t)v1 * HID + fl);
        short8 g2 = *(const short8*)(XbfP + (size_t)v2 * HID + fl);
        short8 g3 = *(const short8*)(XbfP + (size_t)v3 * HID + fl);
        short8 g4 = *(const short8*)(XbfP + (size_t)v4 * HID + fl);
        short8 g5 = *(const short8*)(XbfP + (size_t)v5 * HID + fl);
        short8 g6 = *(const short8*)(XbfP + (size_t)v6 * HID + fl);
        short8 g7 = *(const short8*)(XbfP + (size_t)v7 * HID + fl);
        #pragma unroll
        for (int e = 0; e < 8; ++e) {
            s0[e] += bf2f((u16)g0[e]);
            s1[e] += bf2f((u16)g1[e]);
            s2[e] += bf2f((u16)g2[e]);
            s3[e] += bf2f((u16)g3[e]);
            s0[e] += bf2f((u16)g4[e]);
            s1[e] += bf2f((u16)g5[e]);
            s2[e] += bf2f((u16)g6[e]);
            s3[e] += bf2f((u16)g7[e]);
        }
    }
    for (; i + 16 <= end; i += 16) {
        int v0 = csr[i + 0 + q];
        int v1 = csr[i + 4 + q];
        int v2 = csr[i + 8 + q];
        int v3 = csr[i + 12 + q];
        short8 g0 = *(const short8*)(XbfP + (size_t)v0 * HID + fl);
        short8 g1 = *(const short8*)(XbfP + (size_t)v1 * HID + fl);
        short8 g2 = *(const short8*)(XbfP + (size_t)v2 * HID + fl);
        short8 g3 = *(const short8*)(XbfP + (size_t)v3 * HID + fl);
        #pragma unroll
        for (int e = 0; e < 8; ++e) {
            s0[e] += bf2f((u16)g0[e]);
            s1[e] += bf2f((u16)g1[e]);
            s2[e] += bf2f((u16)g2[e]);
            s3[e] += bf2f((u16)g3[e]);
        }
    }
    for (; i + 4 <= end; i += 4) {
        int v = csr[i + q];
        short8 g = *(const short8*)(XbfP + (size_t)v * HID + fl);
        #pragma unroll
        for (int e = 0; e < 8; ++e) s0[e] += bf2f((u16)g[e]);
    }
    if (i + q < end) {
        int v = csr[i + q];
        short8 g = *(const short8*)(XbfP + (size_t)v * HID + fl);
        #pragma unroll
        for (int e = 0; e < 8; ++e) s1[e] += bf2f((u16)g[e]);
    }

    float t[8];
    #pragma unroll
    for (int e = 0; e < 8; ++e) {
        t[e] = (s0[e] + s1[e]) + (s2[e] + s3[e]);
        t[e] += __shfl_xor(t[e], 16, 64);
        t[e] += __shfl_xor(t[e], 32, 64);
    }

    if (q == 0) {
        const size_t off = (size_t)node * HID + fl;
        float xc[8], xp[8], xn[8];
        *(float4*)&xc[0] = *(const float4*)(Xcur + off);
        *(float4*)&xc[4] = *(const float4*)(Xcur + off + 4);
        if (!FIRST) {
            *(float4*)&xp[0] = *(const float4*)(Xdst + off);
            *(float4*)&xp[4] = *(const float4*)(Xdst + off + 4);
        }
        const float d = degf[node];
        const float c0 = 2.f - H2 * d;
        short8 sv;
        #pragma unroll
        for (int e = 0; e < 8; ++e) {
            float prev = FIRST ? xc[e] : xp[e];
            xn[e] = c0 * xc[e] - prev + H2 * t[e];
            sv[e] = (short)f2bf(xn[e]);
        }
        *(float4*)(Xdst + off)     = *(float4*)&xn[0];
        *(float4*)(Xdst + off + 4) = *(float4*)&xn[4];
        *(short8*)(XbfN + off)     = sv;
    }
}

// ---------------------------------------------------------------------------
// 16-step forward LSTM, ONE dispatch, weights FORCED resident in VGPRs.
// (round-9 proven: 142 us, VGPR 124, MfmaUtil 23%)
// ---------------------------------------------------------------------------
__global__ __launch_bounds__(512, 2) void lstm16w_kernel(
    const u16* __restrict__ Xsnap,       // 16 contiguous snapshots
    u16* __restrict__ hOut,              // h15 out
    const u16* __restrict__ WswzF,
    const float* __restrict__ bih, const float* __restrict__ bhh)
{
    __shared__ __align__(16) u16 hL[32][136];
    const int w = threadIdx.x >> 6;
    const int l = threadIdx.x & 63;
    const int l15 = l & 15, quad = l >> 4;
    const int m0 = blockIdx.x * 32;
    const int kof = quad * 8;
    const int j = w * 16 + l15;

    // zero h (t=0 zero-state)
    {
        const int r  = threadIdx.x >> 4;          // 0..31
        const int cc = (threadIdx.x & 15) * 8;    // 0..120
        short8 z = {};
        *(short8*)&hL[r][cc] = z;
    }

    // ---- preload weight fragments: wf[q][ck], nt = q*8 + w ----
    short8 wf[4][8];
    #pragma unroll
    for (int q = 0; q < 4; ++q)
        #pragma unroll
        for (int ck = 0; ck < 8; ++ck)
            wf[q][ck] = *(const short8*)(WswzF +
                (((size_t)((q * 8 + w) * 8 + ck)) << 9) + (l << 3));
    // force residency: mark each fragment as modified -> no remat from memory
    #pragma unroll
    for (int q = 0; q < 4; ++q)
        #pragma unroll
        for (int ck = 0; ck < 8; ++ck)
            asm volatile("" : "+v"(wf[q][ck]));

    const float bI = bih[j]       + bhh[j];
    const float bF = bih[128 + j] + bhh[128 + j];
    const float bG = bih[256 + j] + bhh[256 + j];
    const float bO = bih[384 + j] + bhh[384 + j];
    float cst[2][4] = {};

    const size_t rowA0 = (size_t)(m0 + l15) * HID + kof;
    const size_t rowA1 = (size_t)(m0 + 16 + l15) * HID + kof;

    // prefetch X fragments for t=0
    short8 xa[4], xb[4];
    #pragma unroll
    for (int ck = 0; ck < 4; ++ck) {
        xa[ck] = *(const short8*)(Xsnap + rowA0 + ck * 32);
        xb[ck] = *(const short8*)(Xsnap + rowA1 + ck * 32);
    }
    __syncthreads();

    // ---- forward LSTM: 16 steps, weights + X in VGPRs, h in LDS ----
    #pragma unroll 1
    for (int t = 0; t < NSTEPS; ++t) {
        f32x4 acc[2][4] = {};
        // X half (ck 0..3) from prefetched regs
        #pragma unroll
        for (int ck = 0; ck < 4; ++ck)
            #pragma unroll
            for (int q = 0; q < 4; ++q) {
                acc[0][q] = __builtin_amdgcn_mfma_f32_16x16x32_bf16(xa[ck], wf[q][ck], acc[0][q], 0, 0, 0);
                acc[1][q] = __builtin_amdgcn_mfma_f32_16x16x32_bf16(xb[ck], wf[q][ck], acc[1][q], 0, 0, 0);
            }
        // issue prefetch for t+1 (latency hides under h-MFMAs + gates)
        if (t + 1 < NSTEPS) {
            const u16* Xn = Xsnap + (size_t)(t + 1) * N_NODES * HID;
            #pragma unroll
            for (int ck = 0; ck < 4; ++ck) {
                xa[ck] = *(const short8*)(Xn + rowA0 + ck * 32);
                xb[ck] = *(const short8*)(Xn + rowA1 + ck * 32);
            }
        }
        // h half (ck 4..7) from LDS
        #pragma unroll
        for (int ck = 4; ck < 8; ++ck) {
            short8 a0 = *(const short8*)(&hL[l15][(ck - 4) * 32 + kof]);
            short8 a1 = *(const short8*)(&hL[16 + l15][(ck - 4) * 32 + kof]);
            #pragma unroll
            for (int q = 0; q < 4; ++q) {
                acc[0][q] = __builtin_amdgcn_mfma_f32_16x16x32_bf16(a0, wf[q][ck], acc[0][q], 0, 0, 0);
                acc[1][q] = __builtin_amdgcn_mfma_f32_16x16x32_bf16(a1, wf[q][ck], acc[1][q], 0, 0, 0);
            }
        }
        __syncthreads();   // all hL reads done before overwrite
        #pragma unroll
        for (int mt = 0; mt < 2; ++mt) {
            #pragma unroll
            for (int i = 0; i < 4; ++i) {
                float gi = sigm_f(acc[mt][0][i] + bI);
                float gf = sigm_f(acc[mt][1][i] + bF);
                float gg = tanh_f(acc[mt][2][i] + bG);
                float go = sigm_f(acc[mt][3][i] + bO);
                float cn = gf * cst[mt][i] + gi * gg;
                cst[mt][i] = cn;
                hL[mt * 16 + quad * 4 + i][j] = f2bf(go * tanh_f(cn));
            }
        }
        __syncthreads();   // hL written before next step's reads
    }

    // write h15 -> global
    {
        const int r  = threadIdx.x >> 4;
        const int cc = (threadIdx.x & 15) * 8;
        *(short8*)(hOut + (size_t)(m0 + r) * HID + cc) = *(const short8*)&hL[r][cc];
    }
}

// ---------------------------------------------------------------------------
// Tail: seed h15 from global -> backward zero-state cell on snap15 -> Hb;
// fc1 ([h15 | h_b]); fc2 -> out. 625 blocks x 512 threads (verbatim phases).
// ---------------------------------------------------------------------------
__global__ __launch_bounds__(512) void tail2_kernel(
    const u16* __restrict__ Xbf15, const u16* __restrict__ h15,
    const u16* __restrict__ WswzB, const u16* __restrict__ WswzH,
    const u16* __restrict__ WswzO,
    const float* __restrict__ bihb, const float* __restrict__ bhhb,
    const float* __restrict__ bf1, const float* __restrict__ bf2_,
    void* __restrict__ out, const int* __restrict__ oflag)
{
    __shared__ __align__(16) u16 hL[32][136];
    __shared__ __align__(16) u16 Hb[32][136];
    __shared__ __align__(16) u16 F1[32][136];
    const int w = threadIdx.x >> 6;
    const int l = threadIdx.x & 63;
    const int l15 = l & 15, quad = l >> 4;
    const int m0 = blockIdx.x * 32;
    const int kof = quad * 8;
    const int j = w * 16 + l15;

    // seed hL := h15
    {
        const int r  = threadIdx.x >> 4;          // 0..31
        const int cc = (threadIdx.x & 15) * 8;    // 0..120
        *(short8*)&hL[r][cc] =
            *(const short8*)(h15 + (size_t)(m0 + r) * HID + cc);
    }

    const size_t rowA0 = (size_t)(m0 + l15) * HID + kof;
    const size_t rowA1 = (size_t)(m0 + 16 + l15) * HID + kof;

    // ---- backward zero-state cell on X_15 -> Hb ----
    {
        f32x4 acc[2][4] = {};
        #pragma unroll
        for (int kc = 0; kc < 128; kc += 32) {
            const int ck = kc >> 5;
            short8 a0 = *(const short8*)(Xbf15 + rowA0 + kc);
            short8 a1 = *(const short8*)(Xbf15 + rowA1 + kc);
            #pragma unroll
            for (int q = 0; q < 4; ++q) {
                int nt = q * 8 + w;
                short8 b = *(const short8*)(WswzB + (((size_t)(nt * 4 + ck)) << 9) + (l << 3));
                acc[0][q] = __builtin_amdgcn_mfma_f32_16x16x32_bf16(a0, b, acc[0][q], 0, 0, 0);
                acc[1][q] = __builtin_amdgcn_mfma_f32_16x16x32_bf16(a1, b, acc[1][q], 0, 0, 0);
            }
        }
        const float cI = bihb[j]       + bhhb[j];
        const float cG = bihb[256 + j] + bhhb[256 + j];
        const float cO = bihb[384 + j] + bhhb[384 + j];
        #pragma unroll
        for (int mt = 0; mt < 2; ++mt)
            #pragma unroll
            for (int i = 0; i < 4; ++i) {
                float gi = sigm(acc[mt][0][i] + cI);
                float gg = tanh_fast(acc[mt][2][i] + cG);
                float go = sigm(acc[mt][3][i] + cO);
                Hb[mt * 16 + quad * 4 + i][j] = f2bf(go * tanh_fast(gi * gg));
            }
    }
    __syncthreads();

    // ---- fc1: [h15 (LDS) | h_b (LDS)] @ Wf1^T -> F1 ----
    {
        f32x4 acc[2] = {};
        #pragma unroll
        for (int kc = 0; kc < 256; kc += 32) {
            const int ck = kc >> 5;
            short8 a0, a1;
            if (kc < 128) {
                a0 = *(const short8*)(&hL[l15][kc + kof]);
                a1 = *(const short8*)(&hL[16 + l15][kc + kof]);
            } else {
                a0 = *(const short8*)(&Hb[l15][(kc - 128) + kof]);
                a1 = *(const short8*)(&Hb[16 + l15][(kc - 128) + kof]);
            }
            short8 b = *(const short8*)(WswzH + (((size_t)(w * 8 + ck)) << 9) + (l << 3));
            acc[0] = __builtin_amdgcn_mfma_f32_16x16x32_bf16(a0, b, acc[0], 0, 0, 0);
            acc[1] = __builtin_amdgcn_mfma_f32_16x16x32_bf16(a1, b, acc[1], 0, 0, 0);
        }
        const float bj = bf1[j];
        #pragma unroll
        for (int mt = 0; mt < 2; ++mt)
            #pragma unroll
            for (int i = 0; i < 4; ++i)
                F1[mt * 16 + quad * 4 + i][j] = f2bf(fmaxf(acc[mt][i] + bj, 0.f));
    }
    __syncthreads();

    // ---- fc2 -> out ----
    {
        const int nt = w & 3, mh = w >> 2;
        f32x4 acc = {};
        #pragma unroll
        for (int kc = 0; kc < 128; kc += 32) {
            const int ck = kc >> 5;
            short8 a = *(const short8*)(&F1[mh * 16 + l15][kc + kof]);
            short8 b = *(const short8*)(WswzO + (((size_t)(nt * 4 + ck)) << 9) + (l << 3));
            acc = __builtin_amdgcn_mfma_f32_16x16x32_bf16(a, b, acc, 0, 0, 0);
        }
        const int jo = nt * 16 + l15;
        const float bj = bf2_[jo];
        const bool obf = (*oflag == 0);
        #pragma unroll
        for (int i = 0; i < 4; ++i) {
            int m = m0 + mh * 16 + quad * 4 + i;
            float o = acc[i] + bj;
            if (obf) ((u16*)out)[(size_t)m * OUT_DIM + jo] = f2bf(o);
            else     ((float*)out)[(size_t)m * OUT_DIM + jo] = o;
        }
    }
}

// ---------------------------------------------------------------------------
extern "C" void kernel_launch(void* const* d_in, const int* in_sizes, int n_in,
                              void* d_out, int out_size, void* d_ws, size_t ws_size,
                              hipStream_t stream)
{
    const void* x  = d_in[0];
    const int*  ei = (const int*)d_in[1];

    const size_t SZ_NH  = (size_t)N_NODES * HID * sizeof(float);   // 10,240,000
    const size_t SZ_NHB = (size_t)N_NODES * HID * sizeof(u16);     //  5,120,000
    const size_t SZ_I   = 80128;

    char* p = (char*)d_ws;
    float* Xa    = (float*)p; p += SZ_NH;
    float* Xb    = (float*)p; p += SZ_NH;      // leapfrog ping-pong partner
    u16*   Xsnap = (u16*)p;   p += (size_t)NSTEPS * SZ_NHB;   // 16 snapshots (82 MB)
    u16*   h15   = (u16*)p;   p += SZ_NHB;     // final forward h
    int*   deg   = (int*)p;   p += SZ_I;
    int*   fill  = (int*)p;   p += SZ_I;
    int*   rowp  = (int*)p;   p += SZ_I;
    float* degf  = (float*)p; p += SZ_I;
    int*   csr   = (int*)p;   p += (size_t)N_EDGES * sizeof(int);
    int*   flag  = (int*)p;   p += 128;
    float* wsf   = (float*)p; p += 272832 * sizeof(float);
    u16*   WswzF  = (u16*)p;  p += 131072 * sizeof(u16);
    u16*   WswzB  = (u16*)p;  p += 65536 * sizeof(u16);
    u16*   WswzH  = (u16*)p;  p += 32768 * sizeof(u16);
    u16*   WswzO  = (u16*)p;  p += 8192 * sizeof(u16);
    u16*   WswzE1 = (u16*)p;  p += 16384 * sizeof(u16);
    u16*   WswzE2 = (u16*)p;  p += 16384 * sizeof(u16);

    // converted f32 weight sub-pointers (offsets match cvt_off)
    float* benc1 = wsf + 16384;
    float* benc2 = wsf + 32896;
    float* bihf  = wsf + 164096;
    float* bhhf  = wsf + 164608;
    float* bihb  = wsf + 230656;
    float* bhhb  = wsf + 231168;
    float* bf1   = wsf + 264448;
    float* bf2_  = wsf + 272768;

    (void)hipMemsetAsync(deg, 0, 2 * SZ_I, stream);     // deg, fill (contiguous)

    // dtype detect + weight conversion (f32 master, swizzled bf16 MFMA copies)
    detect_kernel<<<1, 256, 0, stream>>>((const u16*)x, flag);
    CvtArgs ca;
    ca.s[0] = d_in[2];  ca.s[1] = d_in[3];  ca.s[2] = d_in[4];  ca.s[3] = d_in[5];
    ca.s[4] = d_in[6];  ca.s[5] = d_in[7];  ca.s[6] = d_in[8];  ca.s[7] = d_in[9];
    ca.s[8] = d_in[10]; ca.s[9] = d_in[12]; ca.s[10] = d_in[13];
    ca.s[11] = d_in[14]; ca.s[12] = d_in[15]; ca.s[13] = d_in[16]; ca.s[14] = d_in[17];
    convert_kernel<<<(272832 + 255) / 256, 256, 0, stream>>>(ca, wsf, flag);
    build_wswz_kernel<<<512, 256, 0, stream>>>(wsf, WswzF, WswzB, WswzH, WswzO,
                                               WswzE1, WswzE2);

    // CSR build
    count_kernel<<<(N_EDGES + 255) / 256, 256, 0, stream>>>(ei, deg);
    scan_kernel<<<1, 1024, 0, stream>>>(deg, rowp, degf);
    fill_kernel<<<(N_EDGES + 255) / 256, 256, 0, stream>>>(ei, rowp, fill, csr);

    // fused encoder: x -> X0 (Xa f32 + Xsnap[0] bf16), one dispatch
    encoder_kernel<<<NBLK, 512, 0, stream>>>(x, WswzE1, WswzE2, benc1, benc2,
                                             Xa, Xsnap, flag);

    // 15 pure wave dispatches: X_t snapshot -> slot t
    float* Xc_ = Xa;   // X_{t-1}
    float* Xo_ = Xb;   // X_{t-2} -> overwritten with X_t
    for (int t = 1; t < NSTEPS; ++t) {
        const u16* XbP = Xsnap + (size_t)(t - 1) * N_NODES * HID;
        u16*       XbN = Xsnap + (size_t)t * N_NODES * HID;
        if (t == 1)
            wave_kernel<true><<<N_NODES / 4, 256, 0, stream>>>(
                Xc_, Xo_, XbP, XbN, degf, rowp, csr);
        else
            wave_kernel<false><<<N_NODES / 4, 256, 0, stream>>>(
                Xc_, Xo_, XbP, XbN, degf, rowp, csr);
        float* tf = Xc_; Xc_ = Xo_; Xo_ = tf;
    }

    // 16-step forward LSTM in one dispatch (weights resident in VGPRs) -> h15
    lstm16w_kernel<<<NBLK, 512, 0, stream>>>(Xsnap, h15, WswzF, bihf, bhhf);

    // tail: backward cell + fc1 + fc2 -> out
    tail2_kernel<<<NBLK, 512, 0, stream>>>(
        Xsnap + (size_t)(NSTEPS - 1) * N_NODES * HID, h15,
        WswzB, WswzH, WswzO, bihb, bhhb, bf1, bf2_, d_out, flag);
}

// Round 11
// 699.429 us; speedup vs baseline: 1.0391x; 1.0391x over previous
//
#include <hip/hip_runtime.h>
#include <hip/hip_bf16.h>
#include <cstdint>
#include <cstddef>

#define N_NODES 20000
#define N_EDGES 640000
#define HID     128
#define OUT_DIM 64
#define NSTEPS  16
#define HSTEP   0.1f
#define H2      0.01f          // HSTEP^2 (leapfrog coefficient)
#define NBLK    625            // N_NODES / 32

typedef unsigned short u16;
typedef __attribute__((ext_vector_type(8))) short short8;   // 8 bf16 (4 VGPRs)
typedef __attribute__((ext_vector_type(4))) float f32x4;    // MFMA C/D

__device__ __forceinline__ float bf2f(u16 u) {
    union { unsigned int i; float f; } v; v.i = ((unsigned int)u) << 16; return v.f;
}
__device__ __forceinline__ u16 f2bf(float f) {
    union { float f; unsigned int i; } v; v.f = f;
    unsigned int x = v.i;
    unsigned int r = x + 0x7FFFu + ((x >> 16) & 1u);   // round-to-nearest-even
    return (u16)(r >> 16);
}

__device__ __forceinline__ float sigm(float x) { return 1.f / (1.f + __expf(-x)); }
__device__ __forceinline__ float tanh_fast(float x) {
    float e2 = __expf(-2.f * fabsf(x));
    float t = (1.f - e2) / (1.f + e2);
    return copysignf(t, x);
}

// fast variants (raw v_rcp_f32, rel err ~1e-6 — far below bf16 noise)
__device__ __forceinline__ float rcp_f(float x) { return __builtin_amdgcn_rcpf(x); }
__device__ __forceinline__ float sigm_f(float x) {
    return rcp_f(1.f + __expf(-x));
}
__device__ __forceinline__ float tanh_f(float x) {
    float e2 = __expf(-2.f * fabsf(x));
    float t = (1.f - e2) * rcp_f(1.f + e2);
    return copysignf(t, x);
}

// ---------------------------------------------------------------------------
// Storage-dtype detection. flag=1 -> tensors stored as f32; flag=0 -> bf16.
// ---------------------------------------------------------------------------
__global__ void detect_kernel(const u16* __restrict__ xraw, int* __restrict__ flag) {
    __shared__ int cnt;
    if (threadIdx.x == 0) cnt = 0;
    __syncthreads();
    int c = 0;
    for (int i = threadIdx.x; i < 4096; i += 256) {
        int e = (xraw[i] >> 7) & 0xFF;
        if (e >= 0x90) c++;
    }
    atomicAdd(&cnt, c);
    __syncthreads();
    if (threadIdx.x == 0) *flag = (cnt > 100) ? 1 : 0;
}

// ---------------------------------------------------------------------------
// Packed conversion of the 15 weight/bias tensors into contiguous f32 ws.
// ---------------------------------------------------------------------------
#define N_CVT 15
struct CvtArgs { const void* s[N_CVT]; };
__constant__ const int cvt_off[N_CVT + 1] = {
    0, 16384, 16512, 32896, 33024, 98560, 164096, 164608, 165120,
    230656, 231168, 231680, 264448, 264576, 272768, 272832 };

__global__ void convert_kernel(CvtArgs a, float* __restrict__ dst,
                               const int* __restrict__ flag) {
    int i = blockIdx.x * blockDim.x + threadIdx.x;
    if (i >= 272832) return;
    int seg = 0;
    #pragma unroll
    for (int s = 1; s < N_CVT; ++s) if (i >= cvt_off[s]) seg = s;
    int j = i - cvt_off[seg];
    float v = (*flag) ? ((const float*)a.s[seg])[j]
                      : bf2f(((const u16*)a.s[seg])[j]);
    dst[i] = v;
}

// ---------------------------------------------------------------------------
// Build bf16 weights in MFMA B-fragment-swizzled order.
// elem (nt, ck, lane, j) = W[nt*16 + (lane&15)][ck*32 + (lane>>4)*8 + j]
// flat o = ((nt*NCK + ck)*64 + lane)*8 + j.
// ---------------------------------------------------------------------------
__global__ void build_wswz_kernel(const float* __restrict__ wsf,
                                  u16* __restrict__ WswzF, u16* __restrict__ WswzB,
                                  u16* __restrict__ WswzH, u16* __restrict__ WswzO,
                                  u16* __restrict__ WswzE1, u16* __restrict__ WswzE2) {
    int o = blockIdx.x * blockDim.x + threadIdx.x;
    if (o < 131072) {   // forward [Wihf|Whhf], NCK=8
        int j = o & 7, l = (o >> 3) & 63, rest = o >> 9;
        int ck = rest & 7, nt = rest >> 3;
        int n = nt * 16 + (l & 15);
        int k = ck * 32 + (l >> 4) * 8 + j;
        const float* Wihf = wsf + 33024;
        const float* Whhf = wsf + 98560;
        float v = (k < 128) ? Wihf[n * 128 + k] : Whhf[n * 128 + (k - 128)];
        WswzF[o] = f2bf(v);
    }
    if (o < 65536) {    // backward Wihb, NCK=4
        int j = o & 7, l = (o >> 3) & 63, rest = o >> 9;
        int ck = rest & 3, nt = rest >> 2;
        int n = nt * 16 + (l & 15);
        int k = ck * 32 + (l >> 4) * 8 + j;
        const float* Wihb = wsf + 165120;
        WswzB[o] = f2bf(Wihb[n * 128 + k]);
    }
    if (o < 32768) {    // fc1 Wf1 [128][256], NCK=8
        int j = o & 7, l = (o >> 3) & 63, rest = o >> 9;
        int ck = rest & 7, nt = rest >> 3;
        int n = nt * 16 + (l & 15);
        int k = ck * 32 + (l >> 4) * 8 + j;
        const float* Wf1 = wsf + 231680;
        WswzH[o] = f2bf(Wf1[n * 256 + k]);
    }
    if (o < 8192) {     // fc2 Wf2 [64][128], NCK=4
        int j = o & 7, l = (o >> 3) & 63, rest = o >> 9;
        int ck = rest & 3, nt = rest >> 2;
        int n = nt * 16 + (l & 15);
        int k = ck * 32 + (l >> 4) * 8 + j;
        const float* Wf2 = wsf + 264576;
        WswzO[o] = f2bf(Wf2[n * 128 + k]);
    }
    if (o < 16384) {    // enc1 Wenc1 [128][128], NCK=4, and enc2 Wenc2
        int j = o & 7, l = (o >> 3) & 63, rest = o >> 9;
        int ck = rest & 3, nt = rest >> 2;
        int n = nt * 16 + (l & 15);
        int k = ck * 32 + (l >> 4) * 8 + j;
        const float* We1 = wsf + 0;
        const float* We2 = wsf + 16512;
        WswzE1[o] = f2bf(We1[n * 128 + k]);
        WswzE2[o] = f2bf(We2[n * 128 + k]);
    }
}

// ---------------------------------------------------------------------------
// CSR build: degree count -> exclusive scan -> bucket fill
// ---------------------------------------------------------------------------
__global__ void count_kernel(const int* __restrict__ ei, int* __restrict__ deg) {
    int e = blockIdx.x * blockDim.x + threadIdx.x;
    if (e < N_EDGES) atomicAdd(&deg[ei[N_EDGES + e]], 1);
}

__global__ __launch_bounds__(1024) void scan_kernel(const int* __restrict__ deg,
                                                    int* __restrict__ rowptr,
                                                    float* __restrict__ degf) {
    __shared__ int sd[1024];
    const int t = threadIdx.x;
    const int CH = (N_NODES + 1023) / 1024;   // 20
    int base = t * CH;
    int s = 0;
    for (int i = 0; i < CH; ++i) {
        int idx = base + i;
        if (idx < N_NODES) s += deg[idx];
    }
    sd[t] = s;
    __syncthreads();
    for (int off = 1; off < 1024; off <<= 1) {
        int v = (t >= off) ? sd[t - off] : 0;
        __syncthreads();
        sd[t] += v;
        __syncthreads();
    }
    int run = (t == 0) ? 0 : sd[t - 1];
    for (int i = 0; i < CH; ++i) {
        int idx = base + i;
        if (idx < N_NODES) {
            rowptr[idx] = run;
            degf[idx] = (float)deg[idx];
            run += deg[idx];
        }
    }
    if (t == 1023) rowptr[N_NODES] = sd[1023];
}

__global__ void fill_kernel(const int* __restrict__ ei, const int* __restrict__ rowptr,
                            int* __restrict__ fill, int* __restrict__ csr) {
    int e = blockIdx.x * blockDim.x + threadIdx.x;
    if (e < N_EDGES) {
        int d = ei[N_EDGES + e];
        int p = atomicAdd(&fill[d], 1);
        csr[rowptr[d] + p] = ei[e];
    }
}

// ---------------------------------------------------------------------------
// Fused encoder (one dispatch): enc1 -> H1 (LDS bf16) -> enc2 -> Xa + Xsnap0.
// ---------------------------------------------------------------------------
__global__ __launch_bounds__(512) void encoder_kernel(
    const void* __restrict__ xv,
    const u16* __restrict__ WswzE1, const u16* __restrict__ WswzE2,
    const float* __restrict__ benc1, const float* __restrict__ benc2,
    float* __restrict__ Xa, u16* __restrict__ Xsnap0, const int* __restrict__ flag)
{
    __shared__ __align__(16) u16 H1[32][136];
    const int w = threadIdx.x >> 6;
    const int l = threadIdx.x & 63;
    const int l15 = l & 15, quad = l >> 4;
    const int m0 = blockIdx.x * 32;
    const int kof = quad * 8;
    const int j = w * 16 + l15;
    const bool xf32 = (*flag != 0);

    f32x4 acc[2] = {};
    #pragma unroll
    for (int ck = 0; ck < 4; ++ck) {
        const int kc = ck * 32;
        short8 a0, a1;
        if (xf32) {
            const float* r0 = (const float*)xv + (size_t)(m0 + l15) * HID + kc + kof;
            const float* r1 = (const float*)xv + (size_t)(m0 + 16 + l15) * HID + kc + kof;
            union { u16 u[8]; short8 v; } t0, t1;
            #pragma unroll
            for (int e = 0; e < 8; ++e) { t0.u[e] = f2bf(r0[e]); t1.u[e] = f2bf(r1[e]); }
            a0 = t0.v; a1 = t1.v;
        } else {
            a0 = *(const short8*)((const u16*)xv + (size_t)(m0 + l15) * HID + kc + kof);
            a1 = *(const short8*)((const u16*)xv + (size_t)(m0 + 16 + l15) * HID + kc + kof);
        }
        short8 b = *(const short8*)(WswzE1 + (((size_t)(w * 4 + ck)) << 9) + (l << 3));
        acc[0] = __builtin_amdgcn_mfma_f32_16x16x32_bf16(a0, b, acc[0], 0, 0, 0);
        acc[1] = __builtin_amdgcn_mfma_f32_16x16x32_bf16(a1, b, acc[1], 0, 0, 0);
    }
    {
        const float bj = benc1[j];
        #pragma unroll
        for (int mt = 0; mt < 2; ++mt)
            #pragma unroll
            for (int i = 0; i < 4; ++i)
                H1[mt * 16 + quad * 4 + i][j] = f2bf(fmaxf(acc[mt][i] + bj, 0.f));
    }
    __syncthreads();

    f32x4 acc2[2] = {};
    #pragma unroll
    for (int ck = 0; ck < 4; ++ck) {
        const int kc = ck * 32;
        short8 a0 = *(const short8*)(&H1[l15][kc + kof]);
        short8 a1 = *(const short8*)(&H1[16 + l15][kc + kof]);
        short8 b = *(const short8*)(WswzE2 + (((size_t)(w * 4 + ck)) << 9) + (l << 3));
        acc2[0] = __builtin_amdgcn_mfma_f32_16x16x32_bf16(a0, b, acc2[0], 0, 0, 0);
        acc2[1] = __builtin_amdgcn_mfma_f32_16x16x32_bf16(a1, b, acc2[1], 0, 0, 0);
    }
    {
        const float bj = benc2[j];
        #pragma unroll
        for (int mt = 0; mt < 2; ++mt)
            #pragma unroll
            for (int i = 0; i < 4; ++i) {
                int m = m0 + mt * 16 + quad * 4 + i;
                float o = acc2[mt][i] + bj;
                Xa[(size_t)m * HID + j] = o;
                Xsnap0[(size_t)m * HID + j] = f2bf(o);
            }
    }
}

// ---------------------------------------------------------------------------
// Wave step — LEAPFROG (exact round-9/round-4 body, VGPR<=64 — best measured;
// round-10's 32-edge deep chunk regressed and is reverted).
// ---------------------------------------------------------------------------
template<bool FIRST>
__global__ __launch_bounds__(256) void wave_kernel(
    const float* __restrict__ Xcur, float* __restrict__ Xdst,
    const u16* __restrict__ XbfP, u16* __restrict__ XbfN,
    const float* __restrict__ degf,
    const int* __restrict__ rowptr, const int* __restrict__ csr)
{
    const int node = blockIdx.x * 4 + (threadIdx.x >> 6);
    const int lane = threadIdx.x & 63;
    const int q = lane >> 4;             // edge quarter 0..3
    const int fl = (lane & 15) * 8;      // 8 features per lane

    const int beg = rowptr[node], end = rowptr[node + 1];
    float s0[8] = {}, s1[8] = {}, s2[8] = {}, s3[8] = {};

    int i = beg;
    for (; i + 16 <= end; i += 16) {
        int v0 = csr[i + 0 + q];
        int v1 = csr[i + 4 + q];
        int v2 = csr[i + 8 + q];
        int v3 = csr[i + 12 + q];
        short8 g0 = *(const short8*)(XbfP + (size_t)v0 * HID + fl);
        short8 g1 = *(const short8*)(XbfP + (size_t)v1 * HID + fl);
        short8 g2 = *(const short8*)(XbfP + (size_t)v2 * HID + fl);
        short8 g3 = *(const short8*)(XbfP + (size_t)v3 * HID + fl);
        #pragma unroll
        for (int e = 0; e < 8; ++e) {
            s0[e] += bf2f((u16)g0[e]);
            s1[e] += bf2f((u16)g1[e]);
            s2[e] += bf2f((u16)g2[e]);
            s3[e] += bf2f((u16)g3[e]);
        }
    }
    for (; i + 4 <= end; i += 4) {
        int v = csr[i + q];
        short8 g = *(const short8*)(XbfP + (size_t)v * HID + fl);
        #pragma unroll
        for (int e = 0; e < 8; ++e) s0[e] += bf2f((u16)g[e]);
    }
    if (i + q < end) {
        int v = csr[i + q];
        short8 g = *(const short8*)(XbfP + (size_t)v * HID + fl);
        #pragma unroll
        for (int e = 0; e < 8; ++e) s1[e] += bf2f((u16)g[e]);
    }

    float t[8];
    #pragma unroll
    for (int e = 0; e < 8; ++e) {
        t[e] = (s0[e] + s1[e]) + (s2[e] + s3[e]);
        t[e] += __shfl_xor(t[e], 16, 64);
        t[e] += __shfl_xor(t[e], 32, 64);
    }

    if (q == 0) {
        const size_t off = (size_t)node * HID + fl;
        float xc[8], xp[8], xn[8];
        *(float4*)&xc[0] = *(const float4*)(Xcur + off);
        *(float4*)&xc[4] = *(const float4*)(Xcur + off + 4);
        if (!FIRST) {
            *(float4*)&xp[0] = *(const float4*)(Xdst + off);
            *(float4*)&xp[4] = *(const float4*)(Xdst + off + 4);
        }
        const float d = degf[node];
        const float c0 = 2.f - H2 * d;
        short8 sv;
        #pragma unroll
        for (int e = 0; e < 8; ++e) {
            float prev = FIRST ? xc[e] : xp[e];
            xn[e] = c0 * xc[e] - prev + H2 * t[e];
            sv[e] = (short)f2bf(xn[e]);
        }
        *(float4*)(Xdst + off)     = *(float4*)&xn[0];
        *(float4*)(Xdst + off + 4) = *(float4*)&xn[4];
        *(short8*)(XbfN + off)     = sv;
    }
}

// ---------------------------------------------------------------------------
// 16-step forward LSTM, ONE dispatch, weights resident in VGPRs (round-9
// proven: 142 us, VGPR 124, MfmaUtil 23%), now with hL DOUBLE-BUFFERED:
// step t reads hL[t&1] (MFMA A-operand), gates write hL[(t+1)&1] -> the
// read-before-overwrite hazard is gone and ONE barrier per step suffices
// (was two). Halves the per-step lockstep count; fast waves start step
// t+1's X-MFMAs while slow waves finish step t's gates. t=15 (odd) writes
// buffer 0 -> final h read from hL[0]. Bit-identical math and order.
// ---------------------------------------------------------------------------
__global__ __launch_bounds__(512, 2) void lstm16w_kernel(
    const u16* __restrict__ Xsnap,       // 16 contiguous snapshots
    u16* __restrict__ hOut,              // h15 out
    const u16* __restrict__ WswzF,
    const float* __restrict__ bih, const float* __restrict__ bhh)
{
    __shared__ __align__(16) u16 hL[2][32][136];
    const int w = threadIdx.x >> 6;
    const int l = threadIdx.x & 63;
    const int l15 = l & 15, quad = l >> 4;
    const int m0 = blockIdx.x * 32;
    const int kof = quad * 8;
    const int j = w * 16 + l15;

    // zero h buffer 0 (t=0 zero-state; t=0 reads hL[0])
    {
        const int r  = threadIdx.x >> 4;          // 0..31
        const int cc = (threadIdx.x & 15) * 8;    // 0..120
        short8 z = {};
        *(short8*)&hL[0][r][cc] = z;
    }

    // ---- preload weight fragments: wf[q][ck], nt = q*8 + w ----
    short8 wf[4][8];
    #pragma unroll
    for (int q = 0; q < 4; ++q)
        #pragma unroll
        for (int ck = 0; ck < 8; ++ck)
            wf[q][ck] = *(const short8*)(WswzF +
                (((size_t)((q * 8 + w) * 8 + ck)) << 9) + (l << 3));
    // force residency: mark each fragment as modified -> no remat from memory
    #pragma unroll
    for (int q = 0; q < 4; ++q)
        #pragma unroll
        for (int ck = 0; ck < 8; ++ck)
            asm volatile("" : "+v"(wf[q][ck]));

    const float bI = bih[j]       + bhh[j];
    const float bF = bih[128 + j] + bhh[128 + j];
    const float bG = bih[256 + j] + bhh[256 + j];
    const float bO = bih[384 + j] + bhh[384 + j];
    float cst[2][4] = {};

    const size_t rowA0 = (size_t)(m0 + l15) * HID + kof;
    const size_t rowA1 = (size_t)(m0 + 16 + l15) * HID + kof;

    // prefetch X fragments for t=0
    short8 xa[4], xb[4];
    #pragma unroll
    for (int ck = 0; ck < 4; ++ck) {
        xa[ck] = *(const short8*)(Xsnap + rowA0 + ck * 32);
        xb[ck] = *(const short8*)(Xsnap + rowA1 + ck * 32);
    }
    __syncthreads();

    // ---- forward LSTM: 16 steps, weights + X in VGPRs, h dbuf in LDS ----
    #pragma unroll 1
    for (int t = 0; t < NSTEPS; ++t) {
        const int cur = t & 1, nxt = cur ^ 1;
        f32x4 acc[2][4] = {};
        // X half (ck 0..3) from prefetched regs
        #pragma unroll
        for (int ck = 0; ck < 4; ++ck)
            #pragma unroll
            for (int q = 0; q < 4; ++q) {
                acc[0][q] = __builtin_amdgcn_mfma_f32_16x16x32_bf16(xa[ck], wf[q][ck], acc[0][q], 0, 0, 0);
                acc[1][q] = __builtin_amdgcn_mfma_f32_16x16x32_bf16(xb[ck], wf[q][ck], acc[1][q], 0, 0, 0);
            }
        // issue prefetch for t+1 (latency hides under h-MFMAs + gates)
        if (t + 1 < NSTEPS) {
            const u16* Xn = Xsnap + (size_t)(t + 1) * N_NODES * HID;
            #pragma unroll
            for (int ck = 0; ck < 4; ++ck) {
                xa[ck] = *(const short8*)(Xn + rowA0 + ck * 32);
                xb[ck] = *(const short8*)(Xn + rowA1 + ck * 32);
            }
        }
        // h half (ck 4..7) from LDS buffer `cur`
        #pragma unroll
        for (int ck = 4; ck < 8; ++ck) {
            short8 a0 = *(const short8*)(&hL[cur][l15][(ck - 4) * 32 + kof]);
            short8 a1 = *(const short8*)(&hL[cur][16 + l15][(ck - 4) * 32 + kof]);
            #pragma unroll
            for (int q = 0; q < 4; ++q) {
                acc[0][q] = __builtin_amdgcn_mfma_f32_16x16x32_bf16(a0, wf[q][ck], acc[0][q], 0, 0, 0);
                acc[1][q] = __builtin_amdgcn_mfma_f32_16x16x32_bf16(a1, wf[q][ck], acc[1][q], 0, 0, 0);
            }
        }
        // gates write the OTHER buffer -> no hazard with this step's reads
        #pragma unroll
        for (int mt = 0; mt < 2; ++mt) {
            #pragma unroll
            for (int i = 0; i < 4; ++i) {
                float gi = sigm_f(acc[mt][0][i] + bI);
                float gf = sigm_f(acc[mt][1][i] + bF);
                float gg = tanh_f(acc[mt][2][i] + bG);
                float go = sigm_f(acc[mt][3][i] + bO);
                float cn = gf * cst[mt][i] + gi * gg;
                cst[mt][i] = cn;
                hL[nxt][mt * 16 + quad * 4 + i][j] = f2bf(go * tanh_f(cn));
            }
        }
        __syncthreads();   // h_t visible before step t+1 reads it
    }

    // write h15 -> global (t=15 wrote buffer 0)
    {
        const int r  = threadIdx.x >> 4;
        const int cc = (threadIdx.x & 15) * 8;
        *(short8*)(hOut + (size_t)(m0 + r) * HID + cc) = *(const short8*)&hL[0][r][cc];
    }
}

// ---------------------------------------------------------------------------
// Tail: seed h15 from global -> backward zero-state cell on snap15 -> Hb;
// fc1 ([h15 | h_b]); fc2 -> out. 625 blocks x 512 threads (verbatim phases).
// ---------------------------------------------------------------------------
__global__ __launch_bounds__(512) void tail2_kernel(
    const u16* __restrict__ Xbf15, const u16* __restrict__ h15,
    const u16* __restrict__ WswzB, const u16* __restrict__ WswzH,
    const u16* __restrict__ WswzO,
    const float* __restrict__ bihb, const float* __restrict__ bhhb,
    const float* __restrict__ bf1, const float* __restrict__ bf2_,
    void* __restrict__ out, const int* __restrict__ oflag)
{
    __shared__ __align__(16) u16 hL[32][136];
    __shared__ __align__(16) u16 Hb[32][136];
    __shared__ __align__(16) u16 F1[32][136];
    const int w = threadIdx.x >> 6;
    const int l = threadIdx.x & 63;
    const int l15 = l & 15, quad = l >> 4;
    const int m0 = blockIdx.x * 32;
    const int kof = quad * 8;
    const int j = w * 16 + l15;

    // seed hL := h15
    {
        const int r  = threadIdx.x >> 4;          // 0..31
        const int cc = (threadIdx.x & 15) * 8;    // 0..120
        *(short8*)&hL[r][cc] =
            *(const short8*)(h15 + (size_t)(m0 + r) * HID + cc);
    }

    const size_t rowA0 = (size_t)(m0 + l15) * HID + kof;
    const size_t rowA1 = (size_t)(m0 + 16 + l15) * HID + kof;

    // ---- backward zero-state cell on X_15 -> Hb ----
    {
        f32x4 acc[2][4] = {};
        #pragma unroll
        for (int kc = 0; kc < 128; kc += 32) {
            const int ck = kc >> 5;
            short8 a0 = *(const short8*)(Xbf15 + rowA0 + kc);
            short8 a1 = *(const short8*)(Xbf15 + rowA1 + kc);
            #pragma unroll
            for (int q = 0; q < 4; ++q) {
                int nt = q * 8 + w;
                short8 b = *(const short8*)(WswzB + (((size_t)(nt * 4 + ck)) << 9) + (l << 3));
                acc[0][q] = __builtin_amdgcn_mfma_f32_16x16x32_bf16(a0, b, acc[0][q], 0, 0, 0);
                acc[1][q] = __builtin_amdgcn_mfma_f32_16x16x32_bf16(a1, b, acc[1][q], 0, 0, 0);
            }
        }
        const float cI = bihb[j]       + bhhb[j];
        const float cG = bihb[256 + j] + bhhb[256 + j];
        const float cO = bihb[384 + j] + bhhb[384 + j];
        #pragma unroll
        for (int mt = 0; mt < 2; ++mt)
            #pragma unroll
            for (int i = 0; i < 4; ++i) {
                float gi = sigm(acc[mt][0][i] + cI);
                float gg = tanh_fast(acc[mt][2][i] + cG);
                float go = sigm(acc[mt][3][i] + cO);
                Hb[mt * 16 + quad * 4 + i][j] = f2bf(go * tanh_fast(gi * gg));
            }
    }
    __syncthreads();

    // ---- fc1: [h15 (LDS) | h_b (LDS)] @ Wf1^T -> F1 ----
    {
        f32x4 acc[2] = {};
        #pragma unroll
        for (int kc = 0; kc < 256; kc += 32) {
            const int ck = kc >> 5;
            short8 a0, a1;
            if (kc < 128) {
                a0 = *(const short8*)(&hL[l15][kc + kof]);
                a1 = *(const short8*)(&hL[16 + l15][kc + kof]);
            } else {
                a0 = *(const short8*)(&Hb[l15][(kc - 128) + kof]);
                a1 = *(const short8*)(&Hb[16 + l15][(kc - 128) + kof]);
            }
            short8 b = *(const short8*)(WswzH + (((size_t)(w * 8 + ck)) << 9) + (l << 3));
            acc[0] = __builtin_amdgcn_mfma_f32_16x16x32_bf16(a0, b, acc[0], 0, 0, 0);
            acc[1] = __builtin_amdgcn_mfma_f32_16x16x32_bf16(a1, b, acc[1], 0, 0, 0);
        }
        const float bj = bf1[j];
        #pragma unroll
        for (int mt = 0; mt < 2; ++mt)
            #pragma unroll
            for (int i = 0; i < 4; ++i)
                F1[mt * 16 + quad * 4 + i][j] = f2bf(fmaxf(acc[mt][i] + bj, 0.f));
    }
    __syncthreads();

    // ---- fc2 -> out ----
    {
        const int nt = w & 3, mh = w >> 2;
        f32x4 acc = {};
        #pragma unroll
        for (int kc = 0; kc < 128; kc += 32) {
            const int ck = kc >> 5;
            short8 a = *(const short8*)(&F1[mh * 16 + l15][kc + kof]);
            short8 b = *(const short8*)(WswzO + (((size_t)(nt * 4 + ck)) << 9) + (l << 3));
            acc = __builtin_amdgcn_mfma_f32_16x16x32_bf16(a, b, acc, 0, 0, 0);
        }
        const int jo = nt * 16 + l15;
        const float bj = bf2_[jo];
        const bool obf = (*oflag == 0);
        #pragma unroll
        for (int i = 0; i < 4; ++i) {
            int m = m0 + mh * 16 + quad * 4 + i;
            float o = acc[i] + bj;
            if (obf) ((u16*)out)[(size_t)m * OUT_DIM + jo] = f2bf(o);
            else     ((float*)out)[(size_t)m * OUT_DIM + jo] = o;
        }
    }
}

// ---------------------------------------------------------------------------
extern "C" void kernel_launch(void* const* d_in, const int* in_sizes, int n_in,
                              void* d_out, int out_size, void* d_ws, size_t ws_size,
                              hipStream_t stream)
{
    const void* x  = d_in[0];
    const int*  ei = (const int*)d_in[1];

    const size_t SZ_NH  = (size_t)N_NODES * HID * sizeof(float);   // 10,240,000
    const size_t SZ_NHB = (size_t)N_NODES * HID * sizeof(u16);     //  5,120,000
    const size_t SZ_I   = 80128;

    char* p = (char*)d_ws;
    float* Xa    = (float*)p; p += SZ_NH;
    float* Xb    = (float*)p; p += SZ_NH;      // leapfrog ping-pong partner
    u16*   Xsnap = (u16*)p;   p += (size_t)NSTEPS * SZ_NHB;   // 16 snapshots (82 MB)
    u16*   h15   = (u16*)p;   p += SZ_NHB;     // final forward h
    int*   deg   = (int*)p;   p += SZ_I;
    int*   fill  = (int*)p;   p += SZ_I;
    int*   rowp  = (int*)p;   p += SZ_I;
    float* degf  = (float*)p; p += SZ_I;
    int*   csr   = (int*)p;   p += (size_t)N_EDGES * sizeof(int);
    int*   flag  = (int*)p;   p += 128;
    float* wsf   = (float*)p; p += 272832 * sizeof(float);
    u16*   WswzF  = (u16*)p;  p += 131072 * sizeof(u16);
    u16*   WswzB  = (u16*)p;  p += 65536 * sizeof(u16);
    u16*   WswzH  = (u16*)p;  p += 32768 * sizeof(u16);
    u16*   WswzO  = (u16*)p;  p += 8192 * sizeof(u16);
    u16*   WswzE1 = (u16*)p;  p += 16384 * sizeof(u16);
    u16*   WswzE2 = (u16*)p;  p += 16384 * sizeof(u16);

    // converted f32 weight sub-pointers (offsets match cvt_off)
    float* benc1 = wsf + 16384;
    float* benc2 = wsf + 32896;
    float* bihf  = wsf + 164096;
    float* bhhf  = wsf + 164608;
    float* bihb  = wsf + 230656;
    float* bhhb  = wsf + 231168;
    float* bf1   = wsf + 264448;
    float* bf2_  = wsf + 272768;

    (void)hipMemsetAsync(deg, 0, 2 * SZ_I, stream);     // deg, fill (contiguous)

    // dtype detect + weight conversion (f32 master, swizzled bf16 MFMA copies)
    detect_kernel<<<1, 256, 0, stream>>>((const u16*)x, flag);
    CvtArgs ca;
    ca.s[0] = d_in[2];  ca.s[1] = d_in[3];  ca.s[2] = d_in[4];  ca.s[3] = d_in[5];
    ca.s[4] = d_in[6];  ca.s[5] = d_in[7];  ca.s[6] = d_in[8];  ca.s[7] = d_in[9];
    ca.s[8] = d_in[10]; ca.s[9] = d_in[12]; ca.s[10] = d_in[13];
    ca.s[11] = d_in[14]; ca.s[12] = d_in[15]; ca.s[13] = d_in[16]; ca.s[14] = d_in[17];
    convert_kernel<<<(272832 + 255) / 256, 256, 0, stream>>>(ca, wsf, flag);
    build_wswz_kernel<<<512, 256, 0, stream>>>(wsf, WswzF, WswzB, WswzH, WswzO,
                                               WswzE1, WswzE2);

    // CSR build
    count_kernel<<<(N_EDGES + 255) / 256, 256, 0, stream>>>(ei, deg);
    scan_kernel<<<1, 1024, 0, stream>>>(deg, rowp, degf);
    fill_kernel<<<(N_EDGES + 255) / 256, 256, 0, stream>>>(ei, rowp, fill, csr);

    // fused encoder: x -> X0 (Xa f32 + Xsnap[0] bf16), one dispatch
    encoder_kernel<<<NBLK, 512, 0, stream>>>(x, WswzE1, WswzE2, benc1, benc2,
                                             Xa, Xsnap, flag);

    // 15 pure wave dispatches: X_t snapshot -> slot t
    float* Xc_ = Xa;   // X_{t-1}
    float* Xo_ = Xb;   // X_{t-2} -> overwritten with X_t
    for (int t = 1; t < NSTEPS; ++t) {
        const u16* XbP = Xsnap + (size_t)(t - 1) * N_NODES * HID;
        u16*       XbN = Xsnap + (size_t)t * N_NODES * HID;
        if (t == 1)
            wave_kernel<true><<<N_NODES / 4, 256, 0, stream>>>(
                Xc_, Xo_, XbP, XbN, degf, rowp, csr);
        else
            wave_kernel<false><<<N_NODES / 4, 256, 0, stream>>>(
                Xc_, Xo_, XbP, XbN, degf, rowp, csr);
        float* tf = Xc_; Xc_ = Xo_; Xo_ = tf;
    }

    // 16-step forward LSTM in one dispatch (weights in VGPRs, hL dbuf) -> h15
    lstm16w_kernel<<<NBLK, 512, 0, stream>>>(Xsnap, h15, WswzF, bihf, bhhf);

    // tail: backward cell + fc1 + fc2 -> out
    tail2_kernel<<<NBLK, 512, 0, stream>>>(
        Xsnap + (size_t)(NSTEPS - 1) * N_NODES * HID, h15,
        WswzB, WswzH, WswzO, bihb, bhhb, bf1, bf2_, d_out, flag);
}